// Round 1
// baseline (468.525 us; speedup 1.0000x reference)
//
#include <hip/hip_runtime.h>

#define N_FFT 4096
#define NBINS 2049          // N_FFT/2 + 1
#define NLAGS 81            // 2*MAX_TAU + 1
#define MAXTAU 40
#define PI_D 3.14159265358979323846

// ---------------------------------------------------------------------------
// Kernel 1: naive rfft (DFT) per (b,m) channel, double precision.
// grid: BM*9 blocks of 256 threads; chunk c handles bins c*256..c*256+255,
// chunk 8 handles only bin 2048 (Nyquist).
// S layout: [bm][k][2] doubles (re, im).
// ---------------------------------------------------------------------------
__global__ void dft_kernel(const float* __restrict__ sig,
                           double* __restrict__ S) {
    int bm    = blockIdx.x / 9;
    int chunk = blockIdx.x % 9;

    __shared__ float x[N_FFT];
    const float* sp = sig + (size_t)bm * N_FFT;
    for (int i = threadIdx.x; i < N_FFT; i += blockDim.x) x[i] = sp[i];
    __syncthreads();

    int k = chunk * 256 + (int)threadIdx.x;
    if (k > 2048) return;

    // w = e^{-2*pi*i*k/N}
    double a = -(PI_D / 2048.0) * (double)k;
    double sv, cv;
    sincos(a, &sv, &cv);
    double wr = cv, wi = sv;
    double rr = 1.0, ri = 0.0;   // rotator e^{-2*pi*i*k*t/N}, t = 0
    double ar = 0.0, ai = 0.0;
    for (int t = 0; t < N_FFT; ++t) {
        double xv = (double)x[t];     // LDS broadcast (all lanes same addr)
        ar = fma(xv, rr, ar);
        ai = fma(xv, ri, ai);
        double nr = rr * wr - ri * wi;
        double ni = rr * wi + ri * wr;
        rr = nr; ri = ni;
    }
    size_t o = ((size_t)bm * NBINS + (size_t)k) * 2;
    S[o]     = ar;
    S[o + 1] = ai;
}

// ---------------------------------------------------------------------------
// Kernel 2: per (b,p) pair -> PHAT cross-spectrum -> cc at 81 lags.
// cc[n] = (1/N) * sum_k w_k * Re(phat[k] * e^{+2*pi*i*k*n/N}),
//   w_k = 1 for k=0,2048 else 2;  n = lag-40 in [-40,40].
// 243 threads split (lag, k-chunk): lag = t%81, chunk = t/81 (3 chunks of 683).
// ---------------------------------------------------------------------------
__global__ void phat_cc_kernel(const double* __restrict__ S,
                               const int* __restrict__ comb,
                               double* __restrict__ cc, int P) {
    int b = blockIdx.x / P;
    int p = blockIdx.x % P;
    int ma = comb[p * 2 + 0];
    int mb = comb[p * 2 + 1];
    const double* Sa = S + ((size_t)(b * 8 + ma)) * NBINS * 2;
    const double* Sb = S + ((size_t)(b * 8 + mb)) * NBINS * 2;

    __shared__ double ph[NBINS * 2];     // 32,784 B
    __shared__ double part[243];

    for (int k = threadIdx.x; k < NBINS; k += blockDim.x) {
        double arr = Sa[k * 2], aii = Sa[k * 2 + 1];
        double brr = Sb[k * 2], bii = Sb[k * 2 + 1];
        // X = Sa * conj(Sb)
        double Xr = arr * brr + aii * bii;
        double Xi = aii * brr - arr * bii;
        double mag = sqrt(Xr * Xr + Xi * Xi);
        double inv = 1.0 / (mag + 1e-12);
        ph[k * 2]     = Xr * inv;
        ph[k * 2 + 1] = Xi * inv;
    }
    __syncthreads();

    int t = (int)threadIdx.x;
    if (t < 243) {
        int lag = t % 81;
        int c   = t / 81;
        int n   = lag - MAXTAU;
        int k0  = c * 683;
        int k1  = (k0 + 683 < NBINS) ? (k0 + 683) : NBINS;

        double step = (2.0 * PI_D / (double)N_FFT) * (double)n;
        double sv, cv;
        sincos(step, &sv, &cv);
        double wr = cv, wi = sv;                 // e^{+2*pi*i*n/N}
        sincos(step * (double)k0, &sv, &cv);
        double rr = cv, ri = sv;                 // e^{+2*pi*i*n*k0/N}

        double acc = 0.0;
        for (int k = k0; k < k1; ++k) {
            double w = (k == 0 || k == 2048) ? 1.0 : 2.0;
            acc = fma(w, ph[k * 2] * rr - ph[k * 2 + 1] * ri, acc);
            double nr = rr * wr - ri * wi;
            double ni = rr * wi + ri * wr;
            rr = nr; ri = ni;
        }
        part[t] = acc;
    }
    __syncthreads();
    if (t < 81) {
        double v = (part[t] + part[t + 81] + part[t + 162]) * (1.0 / (double)N_FFT);
        cc[((size_t)b * P + (size_t)p) * NLAGS + (size_t)t] = v;
    }
}

// ---------------------------------------------------------------------------
// Kernel 3: per grid point, per batch: power = sum_p cc[b][p][tau[g][p]];
// block-level argmax (max value, ties -> lowest index, matching np.argmax).
// ---------------------------------------------------------------------------
__global__ void power_argmax_kernel(const double* __restrict__ cc,
                                    const int* __restrict__ tau,
                                    int G, int P, int B,
                                    double* __restrict__ pval,
                                    int* __restrict__ pidx, int nblocks) {
    int g = blockIdx.x * 256 + (int)threadIdx.x;
    bool act = (g < G);
    int taus[32];
    if (act) {
        #pragma unroll
        for (int p = 0; p < 28; ++p) taus[p] = tau[(size_t)g * P + p];
    }
    __shared__ double rv[256];
    __shared__ int    ri[256];

    for (int b = 0; b < B; ++b) {
        double v = -1e300;
        if (act) {
            const double* c = cc + (size_t)b * P * NLAGS;
            v = 0.0;
            #pragma unroll
            for (int p = 0; p < 28; ++p) v += c[p * NLAGS + taus[p]];
        }
        rv[threadIdx.x] = v;
        ri[threadIdx.x] = act ? g : 0x7fffffff;
        __syncthreads();
        for (int s = 128; s > 0; s >>= 1) {
            if ((int)threadIdx.x < s) {
                double v2 = rv[threadIdx.x + s]; int i2 = ri[threadIdx.x + s];
                double v1 = rv[threadIdx.x];     int i1 = ri[threadIdx.x];
                if (v2 > v1 || (v2 == v1 && i2 < i1)) {
                    rv[threadIdx.x] = v2; ri[threadIdx.x] = i2;
                }
            }
            __syncthreads();
        }
        if (threadIdx.x == 0) {
            pval[b * nblocks + blockIdx.x] = rv[0];
            pidx[b * nblocks + blockIdx.x] = ri[0];
        }
        __syncthreads();   // rv/ri reused next b
    }
}

// ---------------------------------------------------------------------------
// Kernel 4: final reduction over blocks + output write.
// ---------------------------------------------------------------------------
__global__ void finalize_kernel(const double* __restrict__ pval,
                                const int* __restrict__ pidx, int nblocks, int B,
                                const float* __restrict__ grid_x,
                                const float* __restrict__ rec_centroid,
                                float* __restrict__ out) {
    int b = (int)threadIdx.x;
    if (b < B) {
        double best = -1e300; int bi = 0x7fffffff;
        for (int j = 0; j < nblocks; ++j) {
            double v = pval[b * nblocks + j];
            int    i = pidx[b * nblocks + j];
            if (v > best || (v == best && i < bi)) { best = v; bi = i; }
        }
        for (int c = 0; c < 3; ++c)
            out[b * 3 + c] = grid_x[(size_t)bi * 3 + c] - rec_centroid[c];
    }
}

extern "C" void kernel_launch(void* const* d_in, const int* in_sizes, int n_in,
                              void* d_out, int out_size, void* d_ws, size_t ws_size,
                              hipStream_t stream) {
    const float* signal       = (const float*)d_in[0];
    const float* grid_x       = (const float*)d_in[1];
    const int*   tau          = (const int*)d_in[2];
    const int*   comb         = (const int*)d_in[3];
    const float* rec_centroid = (const float*)d_in[4];
    float* out = (float*)d_out;

    int G  = in_sizes[1] / 3;          // grid points (~31416)
    int P  = in_sizes[3] / 2;          // 28 pairs
    int BM = in_sizes[0] / N_FFT;      // 128 channels
    int B  = BM / 8;                   // 16 batches

    // workspace layout (doubles)
    double* S  = (double*)d_ws;                    // BM*2049*2 doubles = 4.20 MB
    double* cc = S + (size_t)BM * NBINS * 2;       // B*P*81 doubles    = 290 KB
    int nblocks = (G + 255) / 256;
    double* pval = cc + (size_t)B * P * NLAGS;
    int*    pidx = (int*)(pval + (size_t)B * nblocks);

    dft_kernel<<<BM * 9, 256, 0, stream>>>(signal, S);
    phat_cc_kernel<<<B * P, 256, 0, stream>>>(S, comb, cc, P);
    power_argmax_kernel<<<nblocks, 256, 0, stream>>>(cc, tau, G, P, B, pval, pidx, nblocks);
    finalize_kernel<<<1, 64, 0, stream>>>(pval, pidx, nblocks, B, grid_x, rec_centroid, out);
}

// Round 2
// 201.794 us; speedup vs baseline: 2.3218x; 2.3218x over previous
//
#include <hip/hip_runtime.h>

#define N_FFT 4096
#define NH    2048          // N_FFT/2 (complex FFT length)
#define NBINS 2049          // N_FFT/2 + 1
#define NLAGS 81            // 2*MAX_TAU + 1
#define MAXTAU 40
#define PI_D 3.14159265358979323846

// ---------------------------------------------------------------------------
// Kernel 1: rfft per (b,m) channel, double precision, via packed complex FFT.
//   z[n] = x[2n] + i x[2n+1], Z = FFT_2048(z)  (in-place radix-2 DIT in LDS)
//   X[k] = E + e^{-2pi i k/N} * O,  E = (Zk + conj(Z[-k]))/2,
//                                   O = -i (Zk - conj(Z[-k]))/2
// One block per channel. S layout: [bm][k][2] doubles (re, im).
// ---------------------------------------------------------------------------
__global__ void rfft_kernel(const float* __restrict__ sig,
                            double* __restrict__ S) {
    int bm  = blockIdx.x;
    int tid = (int)threadIdx.x;

    __shared__ double2 data[NH];   // 32 KB
    __shared__ double2 tw[NH / 2]; // 16 KB : tw[j] = e^{-2pi i j / 2048}

    // load packed real pairs
    const float2* sp = (const float2*)(sig + (size_t)bm * N_FFT);
    for (int i = tid; i < NH; i += 256) {
        float2 v = sp[i];
        data[i] = make_double2((double)v.x, (double)v.y);
    }
    // twiddle table
    for (int j = tid; j < NH / 2; j += 256) {
        double sv, cv;
        sincos(-(2.0 * PI_D / (double)NH) * (double)j, &sv, &cv);
        tw[j] = make_double2(cv, sv);
    }
    __syncthreads();

    // bit-reversal permutation (11 bits)
    for (int i = tid; i < NH; i += 256) {
        int j = (int)(__brev((unsigned)i) >> 21);
        if (i < j) { double2 t = data[i]; data[i] = data[j]; data[j] = t; }
    }
    __syncthreads();

    // 11 radix-2 DIT stages
    for (int s = 1; s <= 11; ++s) {
        int half = 1 << (s - 1);
        for (int t = tid; t < NH / 2; t += 256) {
            int g  = t >> (s - 1);
            int j  = t & (half - 1);
            int i0 = (g << s) + j;
            int i1 = i0 + half;
            double2 w = tw[j << (11 - s)];
            double2 u = data[i0];
            double2 v = data[i1];
            double vr = v.x * w.x - v.y * w.y;
            double vi = v.x * w.y + v.y * w.x;
            data[i0] = make_double2(u.x + vr, u.y + vi);
            data[i1] = make_double2(u.x - vr, u.y - vi);
        }
        __syncthreads();
    }

    // real-split postprocess -> X[0..2048]
    double* So = S + (size_t)bm * NBINS * 2;
    for (int k = tid; k < NBINS; k += 256) {
        double2 Zk = data[k & (NH - 1)];
        double2 Zm = data[(NH - k) & (NH - 1)];
        // d = Zk - conj(Zm); ssum = Zk + conj(Zm)
        double er = 0.5 * (Zk.x + Zm.x);
        double ei = 0.5 * (Zk.y - Zm.y);
        double dr = Zk.x - Zm.x;
        double di = Zk.y + Zm.y;
        double orr = 0.5 * di;       // O = -i*d/2
        double oii = -0.5 * dr;
        double sv, cv;
        sincos(-(2.0 * PI_D / (double)N_FFT) * (double)k, &sv, &cv);
        So[k * 2]     = er + cv * orr - sv * oii;
        So[k * 2 + 1] = ei + cv * oii + sv * orr;
    }
}

// ---------------------------------------------------------------------------
// Kernel 2: per (b,p) pair -> PHAT cross-spectrum -> cc at 81 lags.
// ---------------------------------------------------------------------------
__global__ void phat_cc_kernel(const double* __restrict__ S,
                               const int* __restrict__ comb,
                               double* __restrict__ cc, int P) {
    int b = blockIdx.x / P;
    int p = blockIdx.x % P;
    int ma = comb[p * 2 + 0];
    int mb = comb[p * 2 + 1];
    const double* Sa = S + ((size_t)(b * 8 + ma)) * NBINS * 2;
    const double* Sb = S + ((size_t)(b * 8 + mb)) * NBINS * 2;

    __shared__ double ph[NBINS * 2];
    __shared__ double part[243];

    for (int k = threadIdx.x; k < NBINS; k += blockDim.x) {
        double arr = Sa[k * 2], aii = Sa[k * 2 + 1];
        double brr = Sb[k * 2], bii = Sb[k * 2 + 1];
        double Xr = arr * brr + aii * bii;
        double Xi = aii * brr - arr * bii;
        double mag = sqrt(Xr * Xr + Xi * Xi);
        double inv = 1.0 / (mag + 1e-12);
        ph[k * 2]     = Xr * inv;
        ph[k * 2 + 1] = Xi * inv;
    }
    __syncthreads();

    int t = (int)threadIdx.x;
    if (t < 243) {
        int lag = t % 81;
        int c   = t / 81;
        int n   = lag - MAXTAU;
        int k0  = c * 683;
        int k1  = (k0 + 683 < NBINS) ? (k0 + 683) : NBINS;

        double step = (2.0 * PI_D / (double)N_FFT) * (double)n;
        double sv, cv;
        sincos(step, &sv, &cv);
        double wr = cv, wi = sv;
        sincos(step * (double)k0, &sv, &cv);
        double rr = cv, ri = sv;

        double acc = 0.0;
        for (int k = k0; k < k1; ++k) {
            double w = (k == 0 || k == 2048) ? 1.0 : 2.0;
            acc = fma(w, ph[k * 2] * rr - ph[k * 2 + 1] * ri, acc);
            double nr = rr * wr - ri * wi;
            double ni = rr * wi + ri * wr;
            rr = nr; ri = ni;
        }
        part[t] = acc;
    }
    __syncthreads();
    if (t < 81) {
        double v = (part[t] + part[t + 81] + part[t + 162]) * (1.0 / (double)N_FFT);
        cc[((size_t)b * P + (size_t)p) * NLAGS + (size_t)t] = v;
    }
}

// ---------------------------------------------------------------------------
// Kernel 3: per grid point, per batch: power = sum_p cc[b][p][tau[g][p]];
// block argmax (ties -> lowest index, matching np.argmax).
// ---------------------------------------------------------------------------
__global__ void power_argmax_kernel(const double* __restrict__ cc,
                                    const int* __restrict__ tau,
                                    int G, int P, int B,
                                    double* __restrict__ pval,
                                    int* __restrict__ pidx, int nblocks) {
    int g = blockIdx.x * 256 + (int)threadIdx.x;
    bool act = (g < G);
    int taus[32];
    if (act) {
        #pragma unroll
        for (int p = 0; p < 28; ++p) taus[p] = tau[(size_t)g * P + p];
    }
    __shared__ double rv[256];
    __shared__ int    ri[256];

    for (int b = 0; b < B; ++b) {
        double v = -1e300;
        if (act) {
            const double* c = cc + (size_t)b * P * NLAGS;
            v = 0.0;
            #pragma unroll
            for (int p = 0; p < 28; ++p) v += c[p * NLAGS + taus[p]];
        }
        rv[threadIdx.x] = v;
        ri[threadIdx.x] = act ? g : 0x7fffffff;
        __syncthreads();
        for (int s = 128; s > 0; s >>= 1) {
            if ((int)threadIdx.x < s) {
                double v2 = rv[threadIdx.x + s]; int i2 = ri[threadIdx.x + s];
                double v1 = rv[threadIdx.x];     int i1 = ri[threadIdx.x];
                if (v2 > v1 || (v2 == v1 && i2 < i1)) {
                    rv[threadIdx.x] = v2; ri[threadIdx.x] = i2;
                }
            }
            __syncthreads();
        }
        if (threadIdx.x == 0) {
            pval[b * nblocks + blockIdx.x] = rv[0];
            pidx[b * nblocks + blockIdx.x] = ri[0];
        }
        __syncthreads();
    }
}

// ---------------------------------------------------------------------------
// Kernel 4: final reduction over blocks + output write.
// ---------------------------------------------------------------------------
__global__ void finalize_kernel(const double* __restrict__ pval,
                                const int* __restrict__ pidx, int nblocks, int B,
                                const float* __restrict__ grid_x,
                                const float* __restrict__ rec_centroid,
                                float* __restrict__ out) {
    int b = (int)threadIdx.x;
    if (b < B) {
        double best = -1e300; int bi = 0x7fffffff;
        for (int j = 0; j < nblocks; ++j) {
            double v = pval[b * nblocks + j];
            int    i = pidx[b * nblocks + j];
            if (v > best || (v == best && i < bi)) { best = v; bi = i; }
        }
        for (int c = 0; c < 3; ++c)
            out[b * 3 + c] = grid_x[(size_t)bi * 3 + c] - rec_centroid[c];
    }
}

extern "C" void kernel_launch(void* const* d_in, const int* in_sizes, int n_in,
                              void* d_out, int out_size, void* d_ws, size_t ws_size,
                              hipStream_t stream) {
    const float* signal       = (const float*)d_in[0];
    const float* grid_x       = (const float*)d_in[1];
    const int*   tau          = (const int*)d_in[2];
    const int*   comb         = (const int*)d_in[3];
    const float* rec_centroid = (const float*)d_in[4];
    float* out = (float*)d_out;

    int G  = in_sizes[1] / 3;
    int P  = in_sizes[3] / 2;
    int BM = in_sizes[0] / N_FFT;
    int B  = BM / 8;

    double* S  = (double*)d_ws;
    double* cc = S + (size_t)BM * NBINS * 2;
    int nblocks = (G + 255) / 256;
    double* pval = cc + (size_t)B * P * NLAGS;
    int*    pidx = (int*)(pval + (size_t)B * nblocks);

    rfft_kernel<<<BM, 256, 0, stream>>>(signal, S);
    phat_cc_kernel<<<B * P, 256, 0, stream>>>(S, comb, cc, P);
    power_argmax_kernel<<<nblocks, 256, 0, stream>>>(cc, tau, G, P, B, pval, pidx, nblocks);
    finalize_kernel<<<1, 64, 0, stream>>>(pval, pidx, nblocks, B, grid_x, rec_centroid, out);
}

// Round 3
// 137.692 us; speedup vs baseline: 3.4027x; 1.4655x over previous
//
#include <hip/hip_runtime.h>

#define N_FFT 4096
#define NH    2048          // N_FFT/2 (complex FFT length)
#define NBINS 2049          // N_FFT/2 + 1
#define NLAGS 81            // 2*MAX_TAU + 1
#define MAXTAU 40
#define PI_D 3.14159265358979323846

// ---------------------------------------------------------------------------
// Kernel 0: twiddle tables (once per call).
//   tw_fft[j]  = e^{-2*pi*i*j/2048},  j in [0,1024)
//   tw_post[k] = e^{-2*pi*i*k/4096},  k in [0,2049)
// ---------------------------------------------------------------------------
__global__ void table_kernel(double2* __restrict__ tw_fft,
                             double2* __restrict__ tw_post) {
    int idx = blockIdx.x * 256 + (int)threadIdx.x;
    if (idx < 1024) {
        double sv, cv;
        sincos(-(2.0 * PI_D / (double)NH) * (double)idx, &sv, &cv);
        tw_fft[idx] = make_double2(cv, sv);
    } else if (idx < 1024 + NBINS) {
        int k = idx - 1024;
        double sv, cv;
        sincos(-(2.0 * PI_D / (double)N_FFT) * (double)k, &sv, &cv);
        tw_post[k] = make_double2(cv, sv);
    }
}

// ---------------------------------------------------------------------------
// Kernel 1: rfft per (b,m) channel, fp64, packed-complex radix-2 FFT in LDS.
// 1024 threads: 1 butterfly per thread per stage. Bit-reversal fused in load.
// ---------------------------------------------------------------------------
__global__ __launch_bounds__(1024)
void rfft_kernel(const float* __restrict__ sig,
                 const double2* __restrict__ tw_fft,
                 const double2* __restrict__ tw_post,
                 double* __restrict__ S) {
    int bm  = blockIdx.x;
    int tid = (int)threadIdx.x;

    __shared__ double2 data[NH];   // 32 KB

    // load packed real pairs, scatter to bit-reversed position
    const float2* sp = (const float2*)(sig + (size_t)bm * N_FFT);
    for (int i = tid; i < NH; i += 1024) {
        float2 v = sp[i];
        int j = (int)(__brev((unsigned)i) >> 21);   // 11-bit reverse
        data[j] = make_double2((double)v.x, (double)v.y);
    }
    __syncthreads();

    // 11 radix-2 DIT stages, 1024 butterflies each
    for (int s = 1; s <= 11; ++s) {
        int half = 1 << (s - 1);
        int t  = tid;
        int g  = t >> (s - 1);
        int j  = t & (half - 1);
        int i0 = (g << s) + j;
        int i1 = i0 + half;
        double2 w = tw_fft[j << (11 - s)];
        double2 u = data[i0];
        double2 v = data[i1];
        double vr = v.x * w.x - v.y * w.y;
        double vi = v.x * w.y + v.y * w.x;
        data[i0] = make_double2(u.x + vr, u.y + vi);
        data[i1] = make_double2(u.x - vr, u.y - vi);
        __syncthreads();
    }

    // real-split postprocess -> X[0..2048]
    double* So = S + (size_t)bm * NBINS * 2;
    for (int k = tid; k < NBINS; k += 1024) {
        double2 Zk = data[k & (NH - 1)];
        double2 Zm = data[(NH - k) & (NH - 1)];
        double er = 0.5 * (Zk.x + Zm.x);
        double ei = 0.5 * (Zk.y - Zm.y);
        double dr = Zk.x - Zm.x;
        double di = Zk.y + Zm.y;
        double orr = 0.5 * di;       // O = -i*d/2
        double oii = -0.5 * dr;
        double2 w = tw_post[k];
        So[k * 2]     = er + w.x * orr - w.y * oii;
        So[k * 2 + 1] = ei + w.x * oii + w.y * orr;
    }
}

// ---------------------------------------------------------------------------
// Kernel 2: per (b,p) pair -> PHAT cross-spectrum -> cc at 81 lags.
// 512 threads; phase 2: 81 lags x 6 k-chunks of 342 (486 active threads).
// ---------------------------------------------------------------------------
#define NCH 6
#define CHLEN 342
__global__ __launch_bounds__(512)
void phat_cc_kernel(const double* __restrict__ S,
                    const int* __restrict__ comb,
                    double* __restrict__ cc, int P) {
    int b = blockIdx.x / P;
    int p = blockIdx.x % P;
    int ma = comb[p * 2 + 0];
    int mb = comb[p * 2 + 1];
    const double* Sa = S + ((size_t)(b * 8 + ma)) * NBINS * 2;
    const double* Sb = S + ((size_t)(b * 8 + mb)) * NBINS * 2;

    __shared__ double ph[NBINS * 2];       // 32,784 B
    __shared__ double part[NLAGS * NCH];   //  3,888 B

    for (int k = threadIdx.x; k < NBINS; k += blockDim.x) {
        double arr = Sa[k * 2], aii = Sa[k * 2 + 1];
        double brr = Sb[k * 2], bii = Sb[k * 2 + 1];
        double Xr = arr * brr + aii * bii;
        double Xi = aii * brr - arr * bii;
        double mag = sqrt(Xr * Xr + Xi * Xi);
        double inv = 1.0 / (mag + 1e-12);
        ph[k * 2]     = Xr * inv;
        ph[k * 2 + 1] = Xi * inv;
    }
    __syncthreads();

    int t = (int)threadIdx.x;
    if (t < NLAGS * NCH) {
        int lag = t % NLAGS;
        int c   = t / NLAGS;
        int n   = lag - MAXTAU;
        int k0  = c * CHLEN;
        int k1  = (k0 + CHLEN < NBINS) ? (k0 + CHLEN) : NBINS;

        double step = (2.0 * PI_D / (double)N_FFT) * (double)n;
        double sv, cv;
        sincos(step, &sv, &cv);
        double wr = cv, wi = sv;                 // e^{+2*pi*i*n/N}
        sincos(step * (double)k0, &sv, &cv);
        double rr = cv, ri = sv;                 // e^{+2*pi*i*n*k0/N}

        double acc = 0.0;
        for (int k = k0; k < k1; ++k) {
            double w = (k == 0 || k == 2048) ? 1.0 : 2.0;
            acc = fma(w, ph[k * 2] * rr - ph[k * 2 + 1] * ri, acc);
            double nr = rr * wr - ri * wi;
            double ni = rr * wi + ri * wr;
            rr = nr; ri = ni;
        }
        part[t] = acc;
    }
    __syncthreads();
    if (t < NLAGS) {
        double v = 0.0;
        #pragma unroll
        for (int c = 0; c < NCH; ++c) v += part[t + NLAGS * c];
        cc[((size_t)b * P + (size_t)p) * NLAGS + (size_t)t] = v * (1.0 / (double)N_FFT);
    }
}

// ---------------------------------------------------------------------------
// Kernel 3: grid = (chunk, batch). cc[b] staged in LDS; per-thread power;
// wave-shuffle argmax (ties -> lowest index, matching np.argmax).
// ---------------------------------------------------------------------------
__global__ __launch_bounds__(256)
void power_argmax_kernel(const double* __restrict__ cc,
                         const int* __restrict__ tau,
                         int G, int P,
                         double* __restrict__ pval,
                         int* __restrict__ pidx, int nchunks) {
    int b     = (int)blockIdx.y;
    int chunk = (int)blockIdx.x;
    int tid   = (int)threadIdx.x;

    __shared__ double ccs[28 * NLAGS];   // 18,144 B
    const double2* csrc = (const double2*)(cc + (size_t)b * P * NLAGS);
    double2* cdst = (double2*)ccs;
    for (int i = tid; i < 28 * NLAGS / 2; i += 256) cdst[i] = csrc[i];
    __syncthreads();

    int g = chunk * 256 + tid;
    double v = -1e300;
    int    gi = 0x7fffffff;
    if (g < G) {
        const int4* tp = (const int4*)(tau + (size_t)g * 28);  // 112 B rows, 16B-aligned
        v = 0.0;
        #pragma unroll
        for (int q = 0; q < 7; ++q) {
            int4 tv = tp[q];
            v += ccs[(q * 4 + 0) * NLAGS + tv.x];
            v += ccs[(q * 4 + 1) * NLAGS + tv.y];
            v += ccs[(q * 4 + 2) * NLAGS + tv.z];
            v += ccs[(q * 4 + 3) * NLAGS + tv.w];
        }
        gi = g;
    }

    // wave shuffle argmax
    #pragma unroll
    for (int off = 32; off > 0; off >>= 1) {
        double v2 = __shfl_down(v, off);
        int    i2 = __shfl_down(gi, off);
        if (v2 > v || (v2 == v && i2 < gi)) { v = v2; gi = i2; }
    }
    __shared__ double wval[4];
    __shared__ int    widx[4];
    int lane = tid & 63, wv = tid >> 6;
    if (lane == 0) { wval[wv] = v; widx[wv] = gi; }
    __syncthreads();
    if (tid == 0) {
        #pragma unroll
        for (int w = 1; w < 4; ++w) {
            double v2 = wval[w]; int i2 = widx[w];
            if (v2 > v || (v2 == v && i2 < gi)) { v = v2; gi = i2; }
        }
        pval[b * nchunks + chunk] = v;
        pidx[b * nchunks + chunk] = gi;
    }
}

// ---------------------------------------------------------------------------
// Kernel 4: final reduction over chunks (one block per batch, one wave).
// ---------------------------------------------------------------------------
__global__ void finalize_kernel(const double* __restrict__ pval,
                                const int* __restrict__ pidx, int nchunks,
                                const float* __restrict__ grid_x,
                                const float* __restrict__ rec_centroid,
                                float* __restrict__ out) {
    int b = (int)blockIdx.x;
    int l = (int)threadIdx.x;
    double v = -1e300; int gi = 0x7fffffff;
    for (int j = l; j < nchunks; j += 64) {
        double v2 = pval[b * nchunks + j];
        int    i2 = pidx[b * nchunks + j];
        if (v2 > v || (v2 == v && i2 < gi)) { v = v2; gi = i2; }
    }
    #pragma unroll
    for (int off = 32; off > 0; off >>= 1) {
        double v2 = __shfl_down(v, off);
        int    i2 = __shfl_down(gi, off);
        if (v2 > v || (v2 == v && i2 < gi)) { v = v2; gi = i2; }
    }
    if (l == 0) {
        for (int c = 0; c < 3; ++c)
            out[b * 3 + c] = grid_x[(size_t)gi * 3 + c] - rec_centroid[c];
    }
}

extern "C" void kernel_launch(void* const* d_in, const int* in_sizes, int n_in,
                              void* d_out, int out_size, void* d_ws, size_t ws_size,
                              hipStream_t stream) {
    const float* signal       = (const float*)d_in[0];
    const float* grid_x       = (const float*)d_in[1];
    const int*   tau          = (const int*)d_in[2];
    const int*   comb         = (const int*)d_in[3];
    const float* rec_centroid = (const float*)d_in[4];
    float* out = (float*)d_out;

    int G  = in_sizes[1] / 3;          // ~31416 grid points
    int P  = in_sizes[3] / 2;          // 28 pairs
    int BM = in_sizes[0] / N_FFT;      // 128 channels
    int B  = BM / 8;                   // 16 batches

    // workspace layout (8B-aligned throughout)
    double*  S       = (double*)d_ws;                         // BM*2049*2
    double*  cc      = S + (size_t)BM * NBINS * 2;            // B*P*81
    double2* tw_fft  = (double2*)(cc + (size_t)B * P * NLAGS);// 1024
    double2* tw_post = tw_fft + 1024;                         // 2049
    int nchunks = (G + 255) / 256;
    double*  pval = (double*)(tw_post + NBINS);
    int*     pidx = (int*)(pval + (size_t)B * nchunks);

    table_kernel<<<13, 256, 0, stream>>>(tw_fft, tw_post);
    rfft_kernel<<<BM, 1024, 0, stream>>>(signal, tw_fft, tw_post, S);
    phat_cc_kernel<<<B * P, 512, 0, stream>>>(S, comb, cc, P);
    power_argmax_kernel<<<dim3(nchunks, B), 256, 0, stream>>>(cc, tau, G, P, pval, pidx, nchunks);
    finalize_kernel<<<B, 64, 0, stream>>>(pval, pidx, nchunks, grid_x, rec_centroid, out);
}

// Round 4
// 109.078 us; speedup vs baseline: 4.2953x; 1.2623x over previous
//
#include <hip/hip_runtime.h>

#define N_FFT 4096
#define NH    2048          // N_FFT/2 (complex FFT length)
#define NBINS 2049          // N_FFT/2 + 1
#define NLAGS 81            // 2*MAX_TAU + 1
#define MAXTAU 40
#define NSEG  4             // k-segments per (b,p) pair
#define SEGLEN 512
#define PI_D 3.14159265358979323846

// ---------------------------------------------------------------------------
// Kernel 0: twiddle tables (once per call).
// ---------------------------------------------------------------------------
__global__ void table_kernel(double2* __restrict__ tw_fft,
                             double2* __restrict__ tw_post) {
    int idx = blockIdx.x * 256 + (int)threadIdx.x;
    if (idx < 1024) {
        double sv, cv;
        sincos(-(2.0 * PI_D / (double)NH) * (double)idx, &sv, &cv);
        tw_fft[idx] = make_double2(cv, sv);
    } else if (idx < 1024 + NBINS) {
        int k = idx - 1024;
        double sv, cv;
        sincos(-(2.0 * PI_D / (double)N_FFT) * (double)k, &sv, &cv);
        tw_post[k] = make_double2(cv, sv);
    }
}

// ---------------------------------------------------------------------------
// Kernel 1: rfft per (b,m) channel, fp64, packed-complex radix-2 FFT in LDS.
// ---------------------------------------------------------------------------
__global__ __launch_bounds__(1024)
void rfft_kernel(const float* __restrict__ sig,
                 const double2* __restrict__ tw_fft,
                 const double2* __restrict__ tw_post,
                 double* __restrict__ S) {
    int bm  = blockIdx.x;
    int tid = (int)threadIdx.x;

    __shared__ double2 data[NH];   // 32 KB

    const float2* sp = (const float2*)(sig + (size_t)bm * N_FFT);
    for (int i = tid; i < NH; i += 1024) {
        float2 v = sp[i];
        int j = (int)(__brev((unsigned)i) >> 21);   // 11-bit reverse
        data[j] = make_double2((double)v.x, (double)v.y);
    }
    __syncthreads();

    for (int s = 1; s <= 11; ++s) {
        int half = 1 << (s - 1);
        int t  = tid;
        int g  = t >> (s - 1);
        int j  = t & (half - 1);
        int i0 = (g << s) + j;
        int i1 = i0 + half;
        double2 w = tw_fft[j << (11 - s)];
        double2 u = data[i0];
        double2 v = data[i1];
        double vr = v.x * w.x - v.y * w.y;
        double vi = v.x * w.y + v.y * w.x;
        data[i0] = make_double2(u.x + vr, u.y + vi);
        data[i1] = make_double2(u.x - vr, u.y - vi);
        __syncthreads();
    }

    double* So = S + (size_t)bm * NBINS * 2;
    for (int k = tid; k < NBINS; k += 1024) {
        double2 Zk = data[k & (NH - 1)];
        double2 Zm = data[(NH - k) & (NH - 1)];
        double er = 0.5 * (Zk.x + Zm.x);
        double ei = 0.5 * (Zk.y - Zm.y);
        double dr = Zk.x - Zm.x;
        double di = Zk.y + Zm.y;
        double orr = 0.5 * di;       // O = -i*d/2
        double oii = -0.5 * dr;
        double2 w = tw_post[k];
        So[k * 2]     = er + w.x * orr - w.y * oii;
        So[k * 2 + 1] = ei + w.x * oii + w.y * orr;
    }
}

// ---------------------------------------------------------------------------
// Kernel 2: per (b,p,seg): PHAT (w folded) for 512(+1) bins into LDS, then
// lag partials via n/-n symmetry:
//   Cr(n) = sum_k w*phr*cos(2pi k n/N), Ci(n) = sum_k w*phi*sin(2pi k n/N)
//   cc[40+n] += Cr-Ci ; cc[40-n] += Cr+Ci
// Phase 2: 41 |n| values x 6 chunks of 86 bins = 246 threads.
// ---------------------------------------------------------------------------
#define NCH 6
#define CHLEN 86
__global__ __launch_bounds__(256)
void phat_cc_part_kernel(const double* __restrict__ S,
                         const int* __restrict__ comb,
                         double* __restrict__ cc_part, int P) {
    int id  = (int)blockIdx.x;
    int seg = id & (NSEG - 1);
    int bp  = id >> 2;
    int b   = bp / P;
    int p   = bp % P;
    int ma = comb[p * 2 + 0];
    int mb = comb[p * 2 + 1];
    const double2* Sa = (const double2*)(S + ((size_t)(b * 8 + ma)) * NBINS * 2);
    const double2* Sb = (const double2*)(S + ((size_t)(b * 8 + mb)) * NBINS * 2);

    int k0 = seg * SEGLEN;
    int k1 = (seg == NSEG - 1) ? NBINS : (k0 + SEGLEN);   // seg3: 513 bins

    __shared__ double2 phs[SEGLEN + 1];       // 8,208 B
    __shared__ double partCr[41 * NCH];       // 1,968 B
    __shared__ double partCi[41 * NCH];

    int tid = (int)threadIdx.x;
    for (int k = k0 + tid; k < k1; k += 256) {
        double2 a = Sa[k];
        double2 c = Sb[k];
        double Xr = a.x * c.x + a.y * c.y;     // Sa * conj(Sb)
        double Xi = a.y * c.x - a.x * c.y;
        double mag = sqrt(Xr * Xr + Xi * Xi);
        double w = (k == 0 || k == 2048) ? 1.0 : 2.0;
        double inv = w / (mag + 1e-12);
        phs[k - k0] = make_double2(Xr * inv, Xi * inv);
    }
    __syncthreads();

    if (tid < 41 * NCH) {
        int n = tid % 41;                      // |lag| 0..40
        int c = tid / 41;
        int kk0 = k0 + c * CHLEN;
        int kk1 = kk0 + CHLEN;
        if (kk1 > k1) kk1 = k1;

        double step = (2.0 * PI_D / (double)N_FFT) * (double)n;
        double sv, cv;
        sincos(step, &sv, &cv);
        double wr = cv, wi = sv;               // e^{+i step}
        sincos(step * (double)kk0, &sv, &cv);
        double rr = cv, ri = sv;               // e^{+i step kk0}

        double Cr = 0.0, Ci = 0.0;
        for (int k = kk0; k < kk1; ++k) {
            double2 ph = phs[k - k0];
            Cr = fma(ph.x, rr, Cr);
            Ci = fma(ph.y, ri, Ci);
            double nr = rr * wr - ri * wi;
            double ni = rr * wi + ri * wr;
            rr = nr; ri = ni;
        }
        partCr[tid] = Cr;
        partCi[tid] = Ci;
    }
    __syncthreads();

    if (tid < 41) {
        double Cr = 0.0, Ci = 0.0;
        #pragma unroll
        for (int c = 0; c < NCH; ++c) {
            Cr += partCr[tid + 41 * c];
            Ci += partCi[tid + 41 * c];
        }
        double* out = cc_part + ((size_t)bp * NSEG + (size_t)seg) * NLAGS;
        out[MAXTAU + tid] = Cr - Ci;
        if (tid > 0) out[MAXTAU - tid] = Cr + Ci;
    }
}

// ---------------------------------------------------------------------------
// Kernel 2b: cc[bp][lag] = (1/N) * sum_seg cc_part[bp][seg][lag]
// Fixed summation order -> deterministic cc (argmax tie-break preserved).
// ---------------------------------------------------------------------------
__global__ void cc_reduce_kernel(const double* __restrict__ cc_part,
                                 double* __restrict__ cc, int total) {
    int idx = blockIdx.x * 256 + (int)threadIdx.x;
    if (idx >= total) return;
    int bp  = idx / NLAGS;
    int lag = idx % NLAGS;
    const double* src = cc_part + (size_t)bp * NSEG * NLAGS + lag;
    double v = 0.0;
    #pragma unroll
    for (int s = 0; s < NSEG; ++s) v += src[s * NLAGS];
    cc[idx] = v * (1.0 / (double)N_FFT);
}

// ---------------------------------------------------------------------------
// Kernel 3: grid = (chunk, batch). cc[b] staged in LDS; per-thread power;
// wave-shuffle argmax (ties -> lowest index, matching np.argmax).
// ---------------------------------------------------------------------------
__global__ __launch_bounds__(256)
void power_argmax_kernel(const double* __restrict__ cc,
                         const int* __restrict__ tau,
                         int G, int P,
                         double* __restrict__ pval,
                         int* __restrict__ pidx, int nchunks) {
    int b     = (int)blockIdx.y;
    int chunk = (int)blockIdx.x;
    int tid   = (int)threadIdx.x;

    __shared__ double ccs[28 * NLAGS];   // 18,144 B
    const double2* csrc = (const double2*)(cc + (size_t)b * P * NLAGS);
    double2* cdst = (double2*)ccs;
    for (int i = tid; i < 28 * NLAGS / 2; i += 256) cdst[i] = csrc[i];
    __syncthreads();

    int g = chunk * 256 + tid;
    double v = -1e300;
    int    gi = 0x7fffffff;
    if (g < G) {
        const int4* tp = (const int4*)(tau + (size_t)g * 28);
        v = 0.0;
        #pragma unroll
        for (int q = 0; q < 7; ++q) {
            int4 tv = tp[q];
            v += ccs[(q * 4 + 0) * NLAGS + tv.x];
            v += ccs[(q * 4 + 1) * NLAGS + tv.y];
            v += ccs[(q * 4 + 2) * NLAGS + tv.z];
            v += ccs[(q * 4 + 3) * NLAGS + tv.w];
        }
        gi = g;
    }

    #pragma unroll
    for (int off = 32; off > 0; off >>= 1) {
        double v2 = __shfl_down(v, off);
        int    i2 = __shfl_down(gi, off);
        if (v2 > v || (v2 == v && i2 < gi)) { v = v2; gi = i2; }
    }
    __shared__ double wval[4];
    __shared__ int    widx[4];
    int lane = tid & 63, wv = tid >> 6;
    if (lane == 0) { wval[wv] = v; widx[wv] = gi; }
    __syncthreads();
    if (tid == 0) {
        #pragma unroll
        for (int w = 1; w < 4; ++w) {
            double v2 = wval[w]; int i2 = widx[w];
            if (v2 > v || (v2 == v && i2 < gi)) { v = v2; gi = i2; }
        }
        pval[b * nchunks + chunk] = v;
        pidx[b * nchunks + chunk] = gi;
    }
}

// ---------------------------------------------------------------------------
// Kernel 4: final reduction over chunks (one block per batch, one wave).
// ---------------------------------------------------------------------------
__global__ void finalize_kernel(const double* __restrict__ pval,
                                const int* __restrict__ pidx, int nchunks,
                                const float* __restrict__ grid_x,
                                const float* __restrict__ rec_centroid,
                                float* __restrict__ out) {
    int b = (int)blockIdx.x;
    int l = (int)threadIdx.x;
    double v = -1e300; int gi = 0x7fffffff;
    for (int j = l; j < nchunks; j += 64) {
        double v2 = pval[b * nchunks + j];
        int    i2 = pidx[b * nchunks + j];
        if (v2 > v || (v2 == v && i2 < gi)) { v = v2; gi = i2; }
    }
    #pragma unroll
    for (int off = 32; off > 0; off >>= 1) {
        double v2 = __shfl_down(v, off);
        int    i2 = __shfl_down(gi, off);
        if (v2 > v || (v2 == v && i2 < gi)) { v = v2; gi = i2; }
    }
    if (l == 0) {
        for (int c = 0; c < 3; ++c)
            out[b * 3 + c] = grid_x[(size_t)gi * 3 + c] - rec_centroid[c];
    }
}

extern "C" void kernel_launch(void* const* d_in, const int* in_sizes, int n_in,
                              void* d_out, int out_size, void* d_ws, size_t ws_size,
                              hipStream_t stream) {
    const float* signal       = (const float*)d_in[0];
    const float* grid_x       = (const float*)d_in[1];
    const int*   tau          = (const int*)d_in[2];
    const int*   comb         = (const int*)d_in[3];
    const float* rec_centroid = (const float*)d_in[4];
    float* out = (float*)d_out;

    int G  = in_sizes[1] / 3;          // ~31416 grid points
    int P  = in_sizes[3] / 2;          // 28 pairs
    int BM = in_sizes[0] / N_FFT;      // 128 channels
    int B  = BM / 8;                   // 16 batches
    int BP = B * P;                    // 448

    // workspace layout (8B-aligned throughout)
    double*  S       = (double*)d_ws;                          // BM*2049*2
    double*  cc      = S + (size_t)BM * NBINS * 2;             // BP*81
    double*  cc_part = cc + (size_t)BP * NLAGS;                // BP*4*81
    double2* tw_fft  = (double2*)(cc_part + (size_t)BP * NSEG * NLAGS); // 1024
    double2* tw_post = tw_fft + 1024;                          // 2049
    int nchunks = (G + 255) / 256;
    double*  pval = (double*)(tw_post + NBINS);
    int*     pidx = (int*)(pval + (size_t)B * nchunks);

    table_kernel<<<13, 256, 0, stream>>>(tw_fft, tw_post);
    rfft_kernel<<<BM, 1024, 0, stream>>>(signal, tw_fft, tw_post, S);
    phat_cc_part_kernel<<<BP * NSEG, 256, 0, stream>>>(S, comb, cc_part, P);
    cc_reduce_kernel<<<(BP * NLAGS + 255) / 256, 256, 0, stream>>>(cc_part, cc, BP * NLAGS);
    power_argmax_kernel<<<dim3(nchunks, B), 256, 0, stream>>>(cc, tau, G, P, pval, pidx, nchunks);
    finalize_kernel<<<B, 64, 0, stream>>>(pval, pidx, nchunks, grid_x, rec_centroid, out);
}